// Round 9
// baseline (35.350 us; speedup 1.0000x reference)
//
#include <hip/hip_runtime.h>

#define D_MODEL 512
#define D_TOK   504
#define EPS     1e-5f
#define SQRT_D  22.627416997969522f   // sqrt(512)

#define NBLK  4096
#define WPB   4
#define NWAVE (NBLK * WPB)            // 16384 persistent waves
#define ITER  4                       // 65536 / 16384

typedef float f32x4 __attribute__((ext_vector_type(4)));

// R8 memory pattern (nt stores + contiguous lane mapping) + R6 persistent
// distance-1 pipeline: ids preloaded, row j+1 in flight during reduce+store j.
__global__ __launch_bounds__(256) void fused_pipe_kernel(
    const int*   __restrict__ x,
    const float* __restrict__ tok_tab,   // [2048][504]
    const float* __restrict__ typ_tab,   // [5][8]
    const float* __restrict__ gamma,     // [512]
    const float* __restrict__ beta,      // [512]
    float*       __restrict__ out)       // [NWAVE*ITER][512]
{
    const int wave = (int)(blockIdx.x * WPB + (threadIdx.x >> 6));
    const int lane = (int)(threadIdx.x & 63);

    const size_t offA = (size_t)lane * 4;        // elements 0..255
    const size_t offB = 256 + (size_t)lane * 4;  // elements 256..511

    const float4 g0  = *reinterpret_cast<const float4*>(gamma + offA);
    const float4 g1  = *reinterpret_cast<const float4*>(gamma + offB);
    const float4 bb0 = *reinterpret_cast<const float4*>(beta + offA);
    const float4 bb1 = *reinterpret_cast<const float4*>(beta + offB);
    const float4 bs0 = make_float4(bb0.x * SQRT_D, bb0.y * SQRT_D, bb0.z * SQRT_D, bb0.w * SQRT_D);
    const float4 bs1 = make_float4(bb1.x * SQRT_D, bb1.y * SQRT_D, bb1.z * SQRT_D, bb1.w * SQRT_D);

    // preload all ids (independent broadcast loads), then force scalar
    int id[ITER];
#pragma unroll
    for (int j = 0; j < ITER; ++j)
        id[j] = x[wave + j * NWAVE];
#pragma unroll
    for (int j = 0; j < ITER; ++j)
        id[j] = __builtin_amdgcn_readfirstlane(id[j]);

    // part-A pointer: always token row; part-B: lanes 62/63 -> type row
    auto ptrA = [&](int xi) -> const float* {
        return tok_tab + (size_t)xi * D_TOK + offA;
    };
    auto ptrB = [&](int xi) -> const float* {
        const int t = (xi >= 128) + (xi >= 256) + (xi >= 512) + (xi >= 1024);
        const float* pB = tok_tab + (size_t)xi * D_TOK + offB;
        const float* pT = typ_tab + (size_t)t * 8 + (size_t)(lane - 62) * 4;
        return (lane >= 62) ? pT : pB;
    };

    float4 aA, bA, aB, bB;   // two named buffers, all uses compile-time
    aA = *reinterpret_cast<const float4*>(ptrA(id[0]));
    bA = *reinterpret_cast<const float4*>(ptrB(id[0]));

#pragma unroll
    for (int j = 0; j < ITER; ++j) {
        if (j + 1 < ITER) {
            if ((j & 1) == 0) {
                aB = *reinterpret_cast<const float4*>(ptrA(id[j + 1]));
                bB = *reinterpret_cast<const float4*>(ptrB(id[j + 1]));
            } else {
                aA = *reinterpret_cast<const float4*>(ptrA(id[j + 1]));
                bA = *reinterpret_cast<const float4*>(ptrB(id[j + 1]));
            }
        }
        const float4 a = ((j & 1) == 0) ? aA : aB;
        const float4 b = ((j & 1) == 0) ? bA : bB;

        float s  = a.x + a.y + a.z + a.w + b.x + b.y + b.z + b.w;
        float s2 = a.x * a.x + a.y * a.y + a.z * a.z + a.w * a.w
                 + b.x * b.x + b.y * b.y + b.z * b.z + b.w * b.w;
#pragma unroll
        for (int off = 32; off > 0; off >>= 1) {
            s  += __shfl_xor(s,  off, 64);
            s2 += __shfl_xor(s2, off, 64);
        }

        const float inv_n = 1.0f / (float)D_MODEL;
        const float mean  = s * inv_n;
        const float var   = s2 * inv_n - mean * mean;
        const float rs    = rsqrtf(var + EPS) * SQRT_D;

        f32x4 o0, o1;
        o0.x = (a.x - mean) * rs * g0.x + bs0.x;
        o0.y = (a.y - mean) * rs * g0.y + bs0.y;
        o0.z = (a.z - mean) * rs * g0.z + bs0.z;
        o0.w = (a.w - mean) * rs * g0.w + bs0.w;
        o1.x = (b.x - mean) * rs * g1.x + bs1.x;
        o1.y = (b.y - mean) * rs * g1.y + bs1.y;
        o1.z = (b.z - mean) * rs * g1.z + bs1.z;
        o1.w = (b.w - mean) * rs * g1.w + bs1.w;

        float* orow = out + (size_t)(wave + j * NWAVE) * D_MODEL;
        __builtin_nontemporal_store(o0, reinterpret_cast<f32x4*>(orow + offA));
        __builtin_nontemporal_store(o1, reinterpret_cast<f32x4*>(orow + offB));
    }
}

// Fallback: verified R8 kernel (28.8 us) for any other token count.
__global__ __launch_bounds__(256) void musical_emb_kernel(
    const int*   __restrict__ x,
    const float* __restrict__ tok_tab,
    const float* __restrict__ typ_tab,
    const float* __restrict__ gamma,
    const float* __restrict__ beta,
    float*       __restrict__ out,
    int n_tokens)
{
    const int wave = (int)((blockIdx.x * blockDim.x + threadIdx.x) >> 6);
    const int lane = (int)(threadIdx.x & 63);
    if (wave >= n_tokens) return;

    const int xi = x[wave];
    const int t = (xi >= 128) + (xi >= 256) + (xi >= 512) + (xi >= 1024);

    const size_t offA = (size_t)lane * 4;
    const size_t offB = 256 + (size_t)lane * 4;

    const float4 a = *reinterpret_cast<const float4*>(tok_tab + (size_t)xi * D_TOK + offA);
    const float* pB = tok_tab + (size_t)xi * D_TOK + offB;
    const float* pT = typ_tab + (size_t)t * 8 + (size_t)(lane - 62) * 4;
    const float4 b = *reinterpret_cast<const float4*>((lane >= 62) ? pT : pB);

    float s  = a.x + a.y + a.z + a.w + b.x + b.y + b.z + b.w;
    float s2 = a.x * a.x + a.y * a.y + a.z * a.z + a.w * a.w
             + b.x * b.x + b.y * b.y + b.z * b.z + b.w * b.w;

#pragma unroll
    for (int off = 32; off > 0; off >>= 1) {
        s  += __shfl_xor(s,  off, 64);
        s2 += __shfl_xor(s2, off, 64);
    }

    const float inv_n = 1.0f / (float)D_MODEL;
    const float mean  = s * inv_n;
    const float var   = s2 * inv_n - mean * mean;
    const float rs    = rsqrtf(var + EPS) * SQRT_D;

    const float4 g0 = *reinterpret_cast<const float4*>(gamma + offA);
    const float4 g1 = *reinterpret_cast<const float4*>(gamma + offB);
    const float4 b0 = *reinterpret_cast<const float4*>(beta  + offA);
    const float4 b1 = *reinterpret_cast<const float4*>(beta  + offB);

    f32x4 o0, o1;
    o0.x = (a.x - mean) * rs * g0.x + b0.x * SQRT_D;
    o0.y = (a.y - mean) * rs * g0.y + b0.y * SQRT_D;
    o0.z = (a.z - mean) * rs * g0.z + b0.z * SQRT_D;
    o0.w = (a.w - mean) * rs * g0.w + b0.w * SQRT_D;
    o1.x = (b.x - mean) * rs * g1.x + b1.x * SQRT_D;
    o1.y = (b.y - mean) * rs * g1.y + b1.y * SQRT_D;
    o1.z = (b.z - mean) * rs * g1.z + b1.z * SQRT_D;
    o1.w = (b.w - mean) * rs * g1.w + b1.w * SQRT_D;

    float* orow = out + (size_t)wave * D_MODEL;
    __builtin_nontemporal_store(o0, reinterpret_cast<f32x4*>(orow + offA));
    __builtin_nontemporal_store(o1, reinterpret_cast<f32x4*>(orow + offB));
}

extern "C" void kernel_launch(void* const* d_in, const int* in_sizes, int n_in,
                              void* d_out, int out_size, void* d_ws, size_t ws_size,
                              hipStream_t stream) {
    const int*   x       = (const int*)d_in[0];
    const float* tok_tab = (const float*)d_in[1];
    const float* typ_tab = (const float*)d_in[2];
    const float* gamma   = (const float*)d_in[3];
    const float* beta    = (const float*)d_in[4];
    float*       out     = (float*)d_out;

    const int n_tokens = in_sizes[0];   // 65536

    if (n_tokens == NWAVE * ITER) {
        fused_pipe_kernel<<<NBLK, 256, 0, stream>>>(
            x, tok_tab, typ_tab, gamma, beta, out);
    } else {
        musical_emb_kernel<<<(n_tokens * 64 + 255) / 256, 256, 0, stream>>>(
            x, tok_tab, typ_tab, gamma, beta, out, n_tokens);
    }
}

// Round 10
// 28.714 us; speedup vs baseline: 1.2311x; 1.2311x over previous
//
#include <hip/hip_runtime.h>

#define D_MODEL 512
#define D_TOK   504
#define EPS     1e-5f
#define SQRT_D  22.627416997969522f   // sqrt(512)

typedef float f32x4 __attribute__((ext_vector_type(4)));

// Verified R8 kernel (28.8 us): nt stores + fully-contiguous lane mapping.
// Lane l owns elements [4l,4l+4) and [256+4l,256+4l+4): every global
// load/store instruction covers one contiguous 1KB span (16B/lane).
__global__ __launch_bounds__(256) void musical_emb_kernel(
    const int*   __restrict__ x,
    const float* __restrict__ tok_tab,   // [2048][504]
    const float* __restrict__ typ_tab,   // [5][8]
    const float* __restrict__ gamma,     // [512]
    const float* __restrict__ beta,      // [512]
    float*       __restrict__ out,       // [n_tokens][512]
    int n_tokens)
{
    const int wave = (int)((blockIdx.x * blockDim.x + threadIdx.x) >> 6);
    const int lane = (int)(threadIdx.x & 63);
    if (wave >= n_tokens) return;

    const int xi = x[wave];
    const int t = (xi >= 128) + (xi >= 256) + (xi >= 512) + (xi >= 1024);

    const size_t offA = (size_t)lane * 4;        // elements 0..255
    const size_t offB = 256 + (size_t)lane * 4;  // elements 256..511

    // Part A: always token row (elements 0..255 < 504)
    const float4 a = *reinterpret_cast<const float4*>(tok_tab + (size_t)xi * D_TOK + offA);

    // Part B: token row for lanes 0..61; lanes 62/63 take type row [0..3]/[4..7]
    const float* pB = tok_tab + (size_t)xi * D_TOK + offB;
    const float* pT = typ_tab + (size_t)t * 8 + (size_t)(lane - 62) * 4;
    const float4 b = *reinterpret_cast<const float4*>((lane >= 62) ? pT : pB);

    float s  = a.x + a.y + a.z + a.w + b.x + b.y + b.z + b.w;
    float s2 = a.x * a.x + a.y * a.y + a.z * a.z + a.w * a.w
             + b.x * b.x + b.y * b.y + b.z * b.z + b.w * b.w;

#pragma unroll
    for (int off = 32; off > 0; off >>= 1) {
        s  += __shfl_xor(s,  off, 64);
        s2 += __shfl_xor(s2, off, 64);
    }

    const float inv_n = 1.0f / (float)D_MODEL;
    const float mean  = s * inv_n;
    const float var   = s2 * inv_n - mean * mean;
    const float rs    = rsqrtf(var + EPS) * SQRT_D;

    const float4 g0 = *reinterpret_cast<const float4*>(gamma + offA);
    const float4 g1 = *reinterpret_cast<const float4*>(gamma + offB);
    const float4 b0 = *reinterpret_cast<const float4*>(beta  + offA);
    const float4 b1 = *reinterpret_cast<const float4*>(beta  + offB);

    f32x4 o0, o1;
    o0.x = (a.x - mean) * rs * g0.x + b0.x * SQRT_D;
    o0.y = (a.y - mean) * rs * g0.y + b0.y * SQRT_D;
    o0.z = (a.z - mean) * rs * g0.z + b0.z * SQRT_D;
    o0.w = (a.w - mean) * rs * g0.w + b0.w * SQRT_D;
    o1.x = (b.x - mean) * rs * g1.x + b1.x * SQRT_D;
    o1.y = (b.y - mean) * rs * g1.y + b1.y * SQRT_D;
    o1.z = (b.z - mean) * rs * g1.z + b1.z * SQRT_D;
    o1.w = (b.w - mean) * rs * g1.w + b1.w * SQRT_D;

    float* orow = out + (size_t)wave * D_MODEL;
    __builtin_nontemporal_store(o0, reinterpret_cast<f32x4*>(orow + offA));
    __builtin_nontemporal_store(o1, reinterpret_cast<f32x4*>(orow + offB));
}

extern "C" void kernel_launch(void* const* d_in, const int* in_sizes, int n_in,
                              void* d_out, int out_size, void* d_ws, size_t ws_size,
                              hipStream_t stream) {
    const int*   x       = (const int*)d_in[0];
    const float* tok_tab = (const float*)d_in[1];
    const float* typ_tab = (const float*)d_in[2];
    const float* gamma   = (const float*)d_in[3];
    const float* beta    = (const float*)d_in[4];
    float*       out     = (float*)d_out;

    const int n_tokens = in_sizes[0];            // 65536
    const int threads  = 256;
    const int blocks   = (n_tokens * 64 + threads - 1) / threads;

    musical_emb_kernel<<<blocks, threads, 0, stream>>>(
        x, tok_tab, typ_tab, gamma, beta, out, n_tokens);
}